// Round 1
// baseline (931.346 us; speedup 1.0000x reference)
//
#include <hip/hip_runtime.h>

#define CH 128

// ---------------- edge dtype detection (int32 vs int64) ----------------
// If edge_index is int64, every odd 32-bit word is 0 (values < 2^31).
// If int32, odd words are random node ids (nonzero w.h.p.).
__global__ void detect_kernel(const int* __restrict__ ei, int* __restrict__ flag, int nwords) {
    int i = blockIdx.x * blockDim.x + threadIdx.x;
    int w = 2 * i + 1;
    if (w < nwords) {
        if (ei[w] != 0) atomicOr(flag, 1);
    }
}

__device__ __forceinline__ int edge_at(const void* ei, int idx, int is64) {
    if (is64) return (int)((const long long*)ei)[idx];
    return ((const int*)ei)[idx];
}

// ---------------- degree count ----------------
__global__ void count_kernel(const void* __restrict__ ei, const int* __restrict__ flag,
                             int* __restrict__ cnt, int e) {
    int i = blockIdx.x * blockDim.x + threadIdx.x;
    if (i < e) {
        int is64 = (*flag == 0);
        int d = edge_at(ei, e + i, is64);   // dst row
        atomicAdd(&cnt[d], 1);
    }
}

__global__ void dis_kernel(const int* __restrict__ cnt, float* __restrict__ dis, int n) {
    int i = blockIdx.x * blockDim.x + threadIdx.x;
    if (i < n) dis[i] = rsqrtf((float)cnt[i] + 1.0f);
}

// ---------------- exclusive scan over cnt -> row_start (single block) ----------------
__global__ __launch_bounds__(1024) void scan_kernel(const int* __restrict__ cnt,
                                                    int* __restrict__ rs, int n, int e) {
    __shared__ int partial[1024];
    int tid = threadIdx.x;
    int chunk = (n + 1023) / 1024;
    int start = tid * chunk;
    int sum = 0;
    for (int i = 0; i < chunk; ++i) {
        int idx = start + i;
        if (idx < n) sum += cnt[idx];
    }
    partial[tid] = sum;
    __syncthreads();
    for (int off = 1; off < 1024; off <<= 1) {
        int v = (tid >= off) ? partial[tid - off] : 0;
        __syncthreads();
        partial[tid] += v;
        __syncthreads();
    }
    int prefix = (tid == 0) ? 0 : partial[tid - 1];
    for (int i = 0; i < chunk; ++i) {
        int idx = start + i;
        if (idx < n) { rs[idx] = prefix; prefix += cnt[idx]; }
    }
    if (tid == 0) rs[n] = e;
}

// ---------------- CSR scatter ----------------
__global__ void scatter_kernel(const void* __restrict__ ei, const int* __restrict__ flag,
                               const int* __restrict__ rs, int* __restrict__ cursor,
                               int* __restrict__ csr, int e) {
    int i = blockIdx.x * blockDim.x + threadIdx.x;
    if (i < e) {
        int is64 = (*flag == 0);
        int s = edge_at(ei, i, is64);
        int d = edge_at(ei, e + i, is64);
        int pos = rs[d] + atomicAdd(&cursor[d], 1);
        csr[pos] = s;
    }
}

// ---------------- fp32 GEMM: out[r][c] = dis[r] * sum_k X[r][k] W[k][c], 128x128 W ----------------
__global__ __launch_bounds__(256) void gemm128_kernel(
    const float* __restrict__ X, const float* __restrict__ W,
    const float* __restrict__ dis, float* __restrict__ out, int n) {
    __shared__ float xs[64 * 132];     // 64 rows, pad 132 to break bank aliasing
    __shared__ float ws[128 * 128];
    const int tid = threadIdx.x;
    const int base = blockIdx.x * 64;

    {   // load W (4096 float4)
        const float4* Wg = (const float4*)W;
        float4* wl = (float4*)ws;
        #pragma unroll
        for (int i = 0; i < 16; ++i) wl[i * 256 + tid] = Wg[i * 256 + tid];
    }
    #pragma unroll
    for (int i = 0; i < 8; ++i) {      // load X tile (2048 float4)
        int idx = i * 256 + tid;
        int r = idx >> 5;
        int kq = (idx & 31) << 2;
        float4 v = make_float4(0.f, 0.f, 0.f, 0.f);
        if (base + r < n) v = *(const float4*)&X[(size_t)(base + r) * CH + kq];
        *(float4*)&xs[r * 132 + kq] = v;
    }
    __syncthreads();

    const int cg = (tid & 15) << 3;    // 8 cols per thread
    const int rg = (tid >> 4) << 2;    // 4 rows per thread
    float acc[4][8];
    #pragma unroll
    for (int i = 0; i < 4; ++i)
        #pragma unroll
        for (int j = 0; j < 8; ++j) acc[i][j] = 0.f;

    #pragma unroll 4
    for (int k = 0; k < CH; k += 4) {
        float4 xa[4];
        #pragma unroll
        for (int i = 0; i < 4; ++i) xa[i] = *(const float4*)&xs[(rg + i) * 132 + k];
        #pragma unroll
        for (int dk = 0; dk < 4; ++dk) {
            float4 w0 = *(const float4*)&ws[(k + dk) * CH + cg];
            float4 w1 = *(const float4*)&ws[(k + dk) * CH + cg + 4];
            #pragma unroll
            for (int i = 0; i < 4; ++i) {
                float a = (dk == 0) ? xa[i].x : (dk == 1) ? xa[i].y : (dk == 2) ? xa[i].z : xa[i].w;
                acc[i][0] = fmaf(a, w0.x, acc[i][0]);
                acc[i][1] = fmaf(a, w0.y, acc[i][1]);
                acc[i][2] = fmaf(a, w0.z, acc[i][2]);
                acc[i][3] = fmaf(a, w0.w, acc[i][3]);
                acc[i][4] = fmaf(a, w1.x, acc[i][4]);
                acc[i][5] = fmaf(a, w1.y, acc[i][5]);
                acc[i][6] = fmaf(a, w1.z, acc[i][6]);
                acc[i][7] = fmaf(a, w1.w, acc[i][7]);
            }
        }
    }

    #pragma unroll
    for (int i = 0; i < 4; ++i) {
        int r = base + rg + i;
        if (r < n) {
            float d = dis[r];
            float4 o0 = make_float4(acc[i][0]*d, acc[i][1]*d, acc[i][2]*d, acc[i][3]*d);
            float4 o1 = make_float4(acc[i][4]*d, acc[i][5]*d, acc[i][6]*d, acc[i][7]*d);
            *(float4*)&out[(size_t)r * CH + cg] = o0;
            *(float4*)&out[(size_t)r * CH + cg + 4] = o1;
        }
    }
}

// ---------------- aggregation (128 ch): wave per dst ----------------
// out[dst][c] = relu( dis[dst]*(sum_{src in N(dst)} Hs[src][c] + Hs[dst][c]) + bias[c] )
__global__ __launch_bounds__(256) void agg128_kernel(
    const float* __restrict__ Hs, const int* __restrict__ rs, const int* __restrict__ csr,
    const float* __restrict__ dis, const float* __restrict__ bias,
    float* __restrict__ out, int n, int relu) {
    int dst = blockIdx.x * 4 + (threadIdx.x >> 6);
    if (dst >= n) return;
    int lane = threadIdx.x & 63;
    int c = lane * 2;
    float2 acc = *(const float2*)&Hs[(size_t)dst * CH + c];  // self term
    int beg = rs[dst], end = rs[dst + 1];
    for (int i = beg; i < end; ++i) {
        int s = csr[i];
        float2 v = *(const float2*)&Hs[(size_t)s * CH + c];
        acc.x += v.x; acc.y += v.y;
    }
    float d = dis[dst];
    float2 b = *(const float2*)&bias[c];
    float o0 = fmaf(acc.x, d, b.x);
    float o1 = fmaf(acc.y, d, b.y);
    if (relu) { o0 = fmaxf(o0, 0.f); o1 = fmaxf(o1, 0.f); }
    *(float2*)&out[(size_t)dst * CH + c] = make_float2(o0, o1);
}

// ---------------- layer 3 transform (128 -> 2): wave per row ----------------
__global__ __launch_bounds__(256) void gemm_out_kernel(
    const float* __restrict__ H, const float* __restrict__ W3,
    const float* __restrict__ dis, float* __restrict__ H3, int n) {
    int row = blockIdx.x * 4 + (threadIdx.x >> 6);
    int lane = threadIdx.x & 63;
    if (row >= n) return;
    float2 v = *(const float2*)&H[(size_t)row * CH + lane * 2];
    float4 w = *(const float4*)&W3[lane * 4];   // (W3[2l][0],W3[2l][1],W3[2l+1][0],W3[2l+1][1])
    float a0 = v.x * w.x + v.y * w.z;
    float a1 = v.x * w.y + v.y * w.w;
    #pragma unroll
    for (int off = 32; off > 0; off >>= 1) {
        a0 += __shfl_xor(a0, off, 64);
        a1 += __shfl_xor(a1, off, 64);
    }
    if (lane == 0) {
        float d = dis[row];
        H3[row * 2]     = a0 * d;
        H3[row * 2 + 1] = a1 * d;
    }
}

// ---------------- layer 3 aggregation (2 ch): thread per dst ----------------
__global__ void agg_out_kernel(const float* __restrict__ H3, const int* __restrict__ rs,
                               const int* __restrict__ csr, const float* __restrict__ dis,
                               const float* __restrict__ b3, float* __restrict__ out, int n) {
    int dst = blockIdx.x * blockDim.x + threadIdx.x;
    if (dst >= n) return;
    float2 acc = *(const float2*)&H3[dst * 2];
    int beg = rs[dst], end = rs[dst + 1];
    for (int i = beg; i < end; ++i) {
        int s = csr[i];
        float2 v = *(const float2*)&H3[s * 2];
        acc.x += v.x; acc.y += v.y;
    }
    float d = dis[dst];
    out[dst * 2]     = fmaf(acc.x, d, b3[0]);
    out[dst * 2 + 1] = fmaf(acc.y, d, b3[1]);
}

extern "C" void kernel_launch(void* const* d_in, const int* in_sizes, int n_in,
                              void* d_out, int out_size, void* d_ws, size_t ws_size,
                              hipStream_t stream) {
    const float* x  = (const float*)d_in[0];
    const void*  ei = d_in[1];
    const float* W1 = (const float*)d_in[2];
    const float* b1 = (const float*)d_in[3];
    const float* W2 = (const float*)d_in[4];
    const float* b2 = (const float*)d_in[5];
    const float* W3 = (const float*)d_in[6];
    const float* b3 = (const float*)d_in[7];
    float* out = (float*)d_out;

    const int n = in_sizes[0] / CH;      // 100000
    const int e = in_sizes[1] / 2;       // 1600000

    // ---- workspace layout (all 256B aligned) ----
    char* w = (char*)d_ws;
    size_t off = 0;
    auto alloc = [&](size_t bytes) { char* p = w + off; off = (off + bytes + 255) & ~(size_t)255; return p; };
    float* bufA   = (float*)alloc((size_t)n * CH * 4);   // H' (scaled transform output)
    float* bufB   = (float*)alloc((size_t)n * CH * 4);   // h (post-aggregation activations)
    int*   csr    = (int*)  alloc((size_t)e * 4);
    float* dis    = (float*)alloc((size_t)n * 4);
    int*   rs     = (int*)  alloc(((size_t)n + 1) * 4);
    float* H3     = (float*)alloc((size_t)n * 2 * 4);
    // zeroed-per-call region: cnt, cursor, flag (contiguous)
    char* zbase   = w + off;
    int*   cnt    = (int*)  alloc((size_t)n * 4);
    int*   cursor = (int*)  alloc((size_t)n * 4);
    int*   flag   = (int*)  alloc(256);
    size_t zbytes = (size_t)((w + off) - zbase);

    hipMemsetAsync(zbase, 0, zbytes, stream);

    // edge dtype detection
    detect_kernel<<<8, 1024, 0, stream>>>((const int*)ei, flag, 2 * e);

    // degree + normalization
    count_kernel<<<(e + 255) / 256, 256, 0, stream>>>(ei, flag, cnt, e);
    dis_kernel<<<(n + 255) / 256, 256, 0, stream>>>(cnt, dis, n);

    // CSR
    scan_kernel<<<1, 1024, 0, stream>>>(cnt, rs, n, e);
    scatter_kernel<<<(e + 255) / 256, 256, 0, stream>>>(ei, flag, rs, cursor, csr, e);

    const int gemmGrid = (n + 63) / 64;
    const int aggGrid  = (n + 3) / 4;

    // layer 1
    gemm128_kernel<<<gemmGrid, 256, 0, stream>>>(x, W1, dis, bufA, n);
    agg128_kernel<<<aggGrid, 256, 0, stream>>>(bufA, rs, csr, dis, b1, bufB, n, 1);
    // layer 2
    gemm128_kernel<<<gemmGrid, 256, 0, stream>>>(bufB, W2, dis, bufA, n);
    agg128_kernel<<<aggGrid, 256, 0, stream>>>(bufA, rs, csr, dis, b2, bufB, n, 1);
    // layer 3
    gemm_out_kernel<<<aggGrid, 256, 0, stream>>>(bufB, W3, dis, H3, n);
    agg_out_kernel<<<(n + 255) / 256, 256, 0, stream>>>(H3, rs, csr, dis, b3, out, n);
}

// Round 2
// 746.490 us; speedup vs baseline: 1.2476x; 1.2476x over previous
//
#include <hip/hip_runtime.h>

#define CH 128

// ---------------- edge dtype detection (int32 vs int64) ----------------
// If edge_index is int64, every odd 32-bit word is 0 (values < 2^31).
// If int32, odd words are random node ids (nonzero w.h.p.).
__global__ void detect_kernel(const int* __restrict__ ei, int* __restrict__ flag, int nwords) {
    int i = blockIdx.x * blockDim.x + threadIdx.x;
    int w = 2 * i + 1;
    if (w < nwords) {
        if (ei[w] != 0) atomicOr(flag, 1);
    }
}

__device__ __forceinline__ int edge_at(const void* ei, int idx, int is64) {
    if (is64) return (int)((const long long*)ei)[idx];
    return ((const int*)ei)[idx];
}

// ---------------- degree count ----------------
__global__ void count_kernel(const void* __restrict__ ei, const int* __restrict__ flag,
                             int* __restrict__ cnt, int e) {
    int i = blockIdx.x * blockDim.x + threadIdx.x;
    if (i < e) {
        int is64 = (*flag == 0);
        int d = edge_at(ei, e + i, is64);   // dst row
        atomicAdd(&cnt[d], 1);
    }
}

// ---------------- multi-block exclusive scan over cnt -> rs ----------------
// pass 1: per-block (256 elems) reduction -> bsum
__global__ __launch_bounds__(256) void scan_pass1(const int* __restrict__ cnt,
                                                  int* __restrict__ bsum, int n) {
    __shared__ int s[256];
    int i = blockIdx.x * 256 + threadIdx.x;
    s[threadIdx.x] = (i < n) ? cnt[i] : 0;
    __syncthreads();
    #pragma unroll
    for (int off = 128; off > 0; off >>= 1) {
        if (threadIdx.x < off) s[threadIdx.x] += s[threadIdx.x + off];
        __syncthreads();
    }
    if (threadIdx.x == 0) bsum[blockIdx.x] = s[0];
}

// pass 2: single-block exclusive scan of block sums (nb <= 1024)
__global__ __launch_bounds__(1024) void scan_pass2(int* __restrict__ bsum, int nb) {
    __shared__ int s[1024];
    int tid = threadIdx.x;
    int v = (tid < nb) ? bsum[tid] : 0;
    s[tid] = v;
    __syncthreads();
    for (int off = 1; off < 1024; off <<= 1) {
        int t = (tid >= off) ? s[tid - off] : 0;
        __syncthreads();
        s[tid] += t;
        __syncthreads();
    }
    if (tid < nb) bsum[tid] = s[tid] - v;   // exclusive
}

// pass 3: per-block exclusive scan + block offset -> rs; also dis = rsqrt(cnt+1)
__global__ __launch_bounds__(256) void scan_pass3(const int* __restrict__ cnt,
                                                  const int* __restrict__ bsum,
                                                  int* __restrict__ rs,
                                                  float* __restrict__ dis, int n, int e) {
    __shared__ int s[256];
    int i = blockIdx.x * 256 + threadIdx.x;
    int v = (i < n) ? cnt[i] : 0;
    s[threadIdx.x] = v;
    __syncthreads();
    #pragma unroll
    for (int off = 1; off < 256; off <<= 1) {
        int t = (threadIdx.x >= off) ? s[threadIdx.x - off] : 0;
        __syncthreads();
        s[threadIdx.x] += t;
        __syncthreads();
    }
    if (i < n) {
        rs[i] = s[threadIdx.x] - v + bsum[blockIdx.x];
        dis[i] = rsqrtf((float)v + 1.0f);
        if (i == n - 1) rs[n] = e;
    }
}

// ---------------- CSR scatter ----------------
__global__ void scatter_kernel(const void* __restrict__ ei, const int* __restrict__ flag,
                               const int* __restrict__ rs, int* __restrict__ cursor,
                               int* __restrict__ csr, int e) {
    int i = blockIdx.x * blockDim.x + threadIdx.x;
    if (i < e) {
        int is64 = (*flag == 0);
        int s = edge_at(ei, i, is64);
        int d = edge_at(ei, e + i, is64);
        int pos = rs[d] + atomicAdd(&cursor[d], 1);
        csr[pos] = s;
    }
}

// ---------------- fp32 GEMM: out[r][c] = dis[r] * sum_k X[r][k] W[k][c], 128x128 W ----------------
__global__ __launch_bounds__(256) void gemm128_kernel(
    const float* __restrict__ X, const float* __restrict__ W,
    const float* __restrict__ dis, float* __restrict__ out, int n) {
    __shared__ float xs[64 * 132];     // 64 rows, pad 132 to break bank aliasing
    __shared__ float ws[128 * 128];
    const int tid = threadIdx.x;
    const int base = blockIdx.x * 64;

    {   // load W (4096 float4)
        const float4* Wg = (const float4*)W;
        float4* wl = (float4*)ws;
        #pragma unroll
        for (int i = 0; i < 16; ++i) wl[i * 256 + tid] = Wg[i * 256 + tid];
    }
    #pragma unroll
    for (int i = 0; i < 8; ++i) {      // load X tile (2048 float4)
        int idx = i * 256 + tid;
        int r = idx >> 5;
        int kq = (idx & 31) << 2;
        float4 v = make_float4(0.f, 0.f, 0.f, 0.f);
        if (base + r < n) v = *(const float4*)&X[(size_t)(base + r) * CH + kq];
        *(float4*)&xs[r * 132 + kq] = v;
    }
    __syncthreads();

    const int cg = (tid & 15) << 3;    // 8 cols per thread
    const int rg = (tid >> 4) << 2;    // 4 rows per thread
    float acc[4][8];
    #pragma unroll
    for (int i = 0; i < 4; ++i)
        #pragma unroll
        for (int j = 0; j < 8; ++j) acc[i][j] = 0.f;

    #pragma unroll 4
    for (int k = 0; k < CH; k += 4) {
        float4 xa[4];
        #pragma unroll
        for (int i = 0; i < 4; ++i) xa[i] = *(const float4*)&xs[(rg + i) * 132 + k];
        #pragma unroll
        for (int dk = 0; dk < 4; ++dk) {
            float4 w0 = *(const float4*)&ws[(k + dk) * CH + cg];
            float4 w1 = *(const float4*)&ws[(k + dk) * CH + cg + 4];
            #pragma unroll
            for (int i = 0; i < 4; ++i) {
                float a = (dk == 0) ? xa[i].x : (dk == 1) ? xa[i].y : (dk == 2) ? xa[i].z : xa[i].w;
                acc[i][0] = fmaf(a, w0.x, acc[i][0]);
                acc[i][1] = fmaf(a, w0.y, acc[i][1]);
                acc[i][2] = fmaf(a, w0.z, acc[i][2]);
                acc[i][3] = fmaf(a, w0.w, acc[i][3]);
                acc[i][4] = fmaf(a, w1.x, acc[i][4]);
                acc[i][5] = fmaf(a, w1.y, acc[i][5]);
                acc[i][6] = fmaf(a, w1.z, acc[i][6]);
                acc[i][7] = fmaf(a, w1.w, acc[i][7]);
            }
        }
    }

    #pragma unroll
    for (int i = 0; i < 4; ++i) {
        int r = base + rg + i;
        if (r < n) {
            float d = dis[r];
            float4 o0 = make_float4(acc[i][0]*d, acc[i][1]*d, acc[i][2]*d, acc[i][3]*d);
            float4 o1 = make_float4(acc[i][4]*d, acc[i][5]*d, acc[i][6]*d, acc[i][7]*d);
            *(float4*)&out[(size_t)r * CH + cg] = o0;
            *(float4*)&out[(size_t)r * CH + cg + 4] = o1;
        }
    }
}

// ---------------- aggregation (128 ch): wave per dst ----------------
// out[dst][c] = relu( dis[dst]*(sum_{src in N(dst)} Hs[src][c] + Hs[dst][c]) + bias[c] )
__global__ __launch_bounds__(256) void agg128_kernel(
    const float* __restrict__ Hs, const int* __restrict__ rs, const int* __restrict__ csr,
    const float* __restrict__ dis, const float* __restrict__ bias,
    float* __restrict__ out, int n, int relu) {
    int dst = blockIdx.x * 4 + (threadIdx.x >> 6);
    if (dst >= n) return;
    int lane = threadIdx.x & 63;
    int c = lane * 2;
    float2 acc = *(const float2*)&Hs[(size_t)dst * CH + c];  // self term
    int beg = rs[dst], end = rs[dst + 1];
    for (int i = beg; i < end; ++i) {
        int s = csr[i];
        float2 v = *(const float2*)&Hs[(size_t)s * CH + c];
        acc.x += v.x; acc.y += v.y;
    }
    float d = dis[dst];
    float2 b = *(const float2*)&bias[c];
    float o0 = fmaf(acc.x, d, b.x);
    float o1 = fmaf(acc.y, d, b.y);
    if (relu) { o0 = fmaxf(o0, 0.f); o1 = fmaxf(o1, 0.f); }
    *(float2*)&out[(size_t)dst * CH + c] = make_float2(o0, o1);
}

// ---------------- layer 3 transform (128 -> 2): wave per row ----------------
__global__ __launch_bounds__(256) void gemm_out_kernel(
    const float* __restrict__ H, const float* __restrict__ W3,
    const float* __restrict__ dis, float* __restrict__ H3, int n) {
    int row = blockIdx.x * 4 + (threadIdx.x >> 6);
    int lane = threadIdx.x & 63;
    if (row >= n) return;
    float2 v = *(const float2*)&H[(size_t)row * CH + lane * 2];
    float4 w = *(const float4*)&W3[lane * 4];   // (W3[2l][0],W3[2l][1],W3[2l+1][0],W3[2l+1][1])
    float a0 = v.x * w.x + v.y * w.z;
    float a1 = v.x * w.y + v.y * w.w;
    #pragma unroll
    for (int off = 32; off > 0; off >>= 1) {
        a0 += __shfl_xor(a0, off, 64);
        a1 += __shfl_xor(a1, off, 64);
    }
    if (lane == 0) {
        float d = dis[row];
        H3[row * 2]     = a0 * d;
        H3[row * 2 + 1] = a1 * d;
    }
}

// ---------------- layer 3 aggregation (2 ch): thread per dst ----------------
__global__ void agg_out_kernel(const float* __restrict__ H3, const int* __restrict__ rs,
                               const int* __restrict__ csr, const float* __restrict__ dis,
                               const float* __restrict__ b3, float* __restrict__ out, int n) {
    int dst = blockIdx.x * blockDim.x + threadIdx.x;
    if (dst >= n) return;
    float2 acc = *(const float2*)&H3[dst * 2];
    int beg = rs[dst], end = rs[dst + 1];
    for (int i = beg; i < end; ++i) {
        int s = csr[i];
        float2 v = *(const float2*)&H3[s * 2];
        acc.x += v.x; acc.y += v.y;
    }
    float d = dis[dst];
    out[dst * 2]     = fmaf(acc.x, d, b3[0]);
    out[dst * 2 + 1] = fmaf(acc.y, d, b3[1]);
}

extern "C" void kernel_launch(void* const* d_in, const int* in_sizes, int n_in,
                              void* d_out, int out_size, void* d_ws, size_t ws_size,
                              hipStream_t stream) {
    const float* x  = (const float*)d_in[0];
    const void*  ei = d_in[1];
    const float* W1 = (const float*)d_in[2];
    const float* b1 = (const float*)d_in[3];
    const float* W2 = (const float*)d_in[4];
    const float* b2 = (const float*)d_in[5];
    const float* W3 = (const float*)d_in[6];
    const float* b3 = (const float*)d_in[7];
    float* out = (float*)d_out;

    const int n = in_sizes[0] / CH;      // 100000
    const int e = in_sizes[1] / 2;       // 1600000

    // ---- workspace layout (all 256B aligned) ----
    char* w = (char*)d_ws;
    size_t off = 0;
    auto alloc = [&](size_t bytes) { char* p = w + off; off = (off + bytes + 255) & ~(size_t)255; return p; };
    float* bufA   = (float*)alloc((size_t)n * CH * 4);   // H' (scaled transform output)
    float* bufB   = (float*)alloc((size_t)n * CH * 4);   // h (post-aggregation activations)
    int*   csr    = (int*)  alloc((size_t)e * 4);
    float* dis    = (float*)alloc((size_t)n * 4);
    int*   rs     = (int*)  alloc(((size_t)n + 1) * 4);
    float* H3     = (float*)alloc((size_t)n * 2 * 4);
    int*   bsum   = (int*)  alloc(1024 * 4);
    // zeroed-per-call region: cnt, cursor, flag (contiguous)
    char* zbase   = w + off;
    int*   cnt    = (int*)  alloc((size_t)n * 4);
    int*   cursor = (int*)  alloc((size_t)n * 4);
    int*   flag   = (int*)  alloc(256);
    size_t zbytes = (size_t)((w + off) - zbase);

    hipMemsetAsync(zbase, 0, zbytes, stream);

    // edge dtype detection
    detect_kernel<<<8, 1024, 0, stream>>>((const int*)ei, flag, 2 * e);

    // degree count
    count_kernel<<<(e + 255) / 256, 256, 0, stream>>>(ei, flag, cnt, e);

    // multi-block exclusive scan (+ dis fused into pass 3)
    const int nb = (n + 255) / 256;      // 391
    scan_pass1<<<nb, 256, 0, stream>>>(cnt, bsum, n);
    scan_pass2<<<1, 1024, 0, stream>>>(bsum, nb);
    scan_pass3<<<nb, 256, 0, stream>>>(cnt, bsum, rs, dis, n, e);

    // CSR
    scatter_kernel<<<(e + 255) / 256, 256, 0, stream>>>(ei, flag, rs, cursor, csr, e);

    const int gemmGrid = (n + 63) / 64;
    const int aggGrid  = (n + 3) / 4;

    // layer 1
    gemm128_kernel<<<gemmGrid, 256, 0, stream>>>(x, W1, dis, bufA, n);
    agg128_kernel<<<aggGrid, 256, 0, stream>>>(bufA, rs, csr, dis, b1, bufB, n, 1);
    // layer 2
    gemm128_kernel<<<gemmGrid, 256, 0, stream>>>(bufB, W2, dis, bufA, n);
    agg128_kernel<<<aggGrid, 256, 0, stream>>>(bufA, rs, csr, dis, b2, bufB, n, 1);
    // layer 3
    gemm_out_kernel<<<aggGrid, 256, 0, stream>>>(bufB, W3, dis, H3, n);
    agg_out_kernel<<<(n + 255) / 256, 256, 0, stream>>>(H3, rs, csr, dis, b3, out, n);
}

// Round 3
// 645.834 us; speedup vs baseline: 1.4421x; 1.1559x over previous
//
#include <hip/hip_runtime.h>

#define CH 128

// ---------------- edge dtype detection (int32 vs int64) ----------------
__global__ void detect_kernel(const int* __restrict__ ei, int* __restrict__ flag, int nwords) {
    int i = blockIdx.x * blockDim.x + threadIdx.x;
    int w = 2 * i + 1;
    if (w < nwords) {
        if (ei[w] != 0) atomicOr(flag, 1);
    }
}

__device__ __forceinline__ int edge_at(const void* ei, int idx, int is64) {
    if (is64) return (int)((const long long*)ei)[idx];
    return ((const int*)ei)[idx];
}

// ---------------- degree count ----------------
__global__ void count_kernel(const void* __restrict__ ei, const int* __restrict__ flag,
                             int* __restrict__ cnt, int e) {
    int i = blockIdx.x * blockDim.x + threadIdx.x;
    if (i < e) {
        int is64 = (*flag == 0);
        int d = edge_at(ei, e + i, is64);   // dst row
        atomicAdd(&cnt[d], 1);
    }
}

// ---------------- multi-block exclusive scan over cnt -> rs ----------------
__global__ __launch_bounds__(256) void scan_pass1(const int* __restrict__ cnt,
                                                  int* __restrict__ bsum, int n) {
    __shared__ int s[256];
    int i = blockIdx.x * 256 + threadIdx.x;
    s[threadIdx.x] = (i < n) ? cnt[i] : 0;
    __syncthreads();
    #pragma unroll
    for (int off = 128; off > 0; off >>= 1) {
        if (threadIdx.x < off) s[threadIdx.x] += s[threadIdx.x + off];
        __syncthreads();
    }
    if (threadIdx.x == 0) bsum[blockIdx.x] = s[0];
}

__global__ __launch_bounds__(1024) void scan_pass2(int* __restrict__ bsum, int nb) {
    __shared__ int s[1024];
    int tid = threadIdx.x;
    int v = (tid < nb) ? bsum[tid] : 0;
    s[tid] = v;
    __syncthreads();
    for (int off = 1; off < 1024; off <<= 1) {
        int t = (tid >= off) ? s[tid - off] : 0;
        __syncthreads();
        s[tid] += t;
        __syncthreads();
    }
    if (tid < nb) bsum[tid] = s[tid] - v;   // exclusive
}

__global__ __launch_bounds__(256) void scan_pass3(const int* __restrict__ cnt,
                                                  const int* __restrict__ bsum,
                                                  int* __restrict__ rs,
                                                  float* __restrict__ dis, int n, int e) {
    __shared__ int s[256];
    int i = blockIdx.x * 256 + threadIdx.x;
    int v = (i < n) ? cnt[i] : 0;
    s[threadIdx.x] = v;
    __syncthreads();
    #pragma unroll
    for (int off = 1; off < 256; off <<= 1) {
        int t = (threadIdx.x >= off) ? s[threadIdx.x - off] : 0;
        __syncthreads();
        s[threadIdx.x] += t;
        __syncthreads();
    }
    if (i < n) {
        rs[i] = s[threadIdx.x] - v + bsum[blockIdx.x];
        dis[i] = rsqrtf((float)v + 1.0f);
        if (i == n - 1) rs[n] = e;
    }
}

// ---------------- CSR scatter ----------------
__global__ void scatter_kernel(const void* __restrict__ ei, const int* __restrict__ flag,
                               const int* __restrict__ rs, int* __restrict__ cursor,
                               int* __restrict__ csr, int e) {
    int i = blockIdx.x * blockDim.x + threadIdx.x;
    if (i < e) {
        int is64 = (*flag == 0);
        int s = edge_at(ei, i, is64);
        int d = edge_at(ei, e + i, is64);
        int pos = rs[d] + atomicAdd(&cursor[d], 1);
        csr[pos] = s;
    }
}

// ---------------- fp32 GEMM: out[r][c] = dis[r] * sum_k X[r][k] W[k][c], 128x128 W ----------------
__global__ __launch_bounds__(256) void gemm128_kernel(
    const float* __restrict__ X, const float* __restrict__ W,
    const float* __restrict__ dis, float* __restrict__ out, int n) {
    __shared__ float xs[64 * 132];
    __shared__ float ws[128 * 128];
    const int tid = threadIdx.x;
    const int base = blockIdx.x * 64;

    {
        const float4* Wg = (const float4*)W;
        float4* wl = (float4*)ws;
        #pragma unroll
        for (int i = 0; i < 16; ++i) wl[i * 256 + tid] = Wg[i * 256 + tid];
    }
    #pragma unroll
    for (int i = 0; i < 8; ++i) {
        int idx = i * 256 + tid;
        int r = idx >> 5;
        int kq = (idx & 31) << 2;
        float4 v = make_float4(0.f, 0.f, 0.f, 0.f);
        if (base + r < n) v = *(const float4*)&X[(size_t)(base + r) * CH + kq];
        *(float4*)&xs[r * 132 + kq] = v;
    }
    __syncthreads();

    const int cg = (tid & 15) << 3;
    const int rg = (tid >> 4) << 2;
    float acc[4][8];
    #pragma unroll
    for (int i = 0; i < 4; ++i)
        #pragma unroll
        for (int j = 0; j < 8; ++j) acc[i][j] = 0.f;

    #pragma unroll 4
    for (int k = 0; k < CH; k += 4) {
        float4 xa[4];
        #pragma unroll
        for (int i = 0; i < 4; ++i) xa[i] = *(const float4*)&xs[(rg + i) * 132 + k];
        #pragma unroll
        for (int dk = 0; dk < 4; ++dk) {
            float4 w0 = *(const float4*)&ws[(k + dk) * CH + cg];
            float4 w1 = *(const float4*)&ws[(k + dk) * CH + cg + 4];
            #pragma unroll
            for (int i = 0; i < 4; ++i) {
                float a = (dk == 0) ? xa[i].x : (dk == 1) ? xa[i].y : (dk == 2) ? xa[i].z : xa[i].w;
                acc[i][0] = fmaf(a, w0.x, acc[i][0]);
                acc[i][1] = fmaf(a, w0.y, acc[i][1]);
                acc[i][2] = fmaf(a, w0.z, acc[i][2]);
                acc[i][3] = fmaf(a, w0.w, acc[i][3]);
                acc[i][4] = fmaf(a, w1.x, acc[i][4]);
                acc[i][5] = fmaf(a, w1.y, acc[i][5]);
                acc[i][6] = fmaf(a, w1.z, acc[i][6]);
                acc[i][7] = fmaf(a, w1.w, acc[i][7]);
            }
        }
    }

    #pragma unroll
    for (int i = 0; i < 4; ++i) {
        int r = base + rg + i;
        if (r < n) {
            float d = dis[r];
            float4 o0 = make_float4(acc[i][0]*d, acc[i][1]*d, acc[i][2]*d, acc[i][3]*d);
            float4 o1 = make_float4(acc[i][4]*d, acc[i][5]*d, acc[i][6]*d, acc[i][7]*d);
            *(float4*)&out[(size_t)r * CH + cg] = o0;
            *(float4*)&out[(size_t)r * CH + cg + 4] = o1;
        }
    }
}

// ---------------- aggregation (128 ch): wave per dst, 4-deep MLP unroll ----------------
// out[dst][c] = relu( dis[dst]*(sum_{src in N(dst)} Hs[src][c] + Hs[dst][c]) + bias[c] )
__global__ __launch_bounds__(256) void agg128_kernel(
    const float* __restrict__ Hs, const int* __restrict__ rs, const int* __restrict__ csr,
    const float* __restrict__ dis, const float* __restrict__ bias,
    float* __restrict__ out, int n, int relu) {
    int dst = blockIdx.x * 4 + (threadIdx.x >> 6);
    if (dst >= n) return;
    int lane = threadIdx.x & 63;
    int c = lane * 2;
    float2 acc = *(const float2*)&Hs[(size_t)dst * CH + c];  // self term
    int beg = rs[dst], end = rs[dst + 1];
    int last = end - 1;
    for (int i = beg; i < end; i += 4) {
        // clamped indices keep the wave lockstep; dup loads hit cache
        int i1 = i + 1 <= last ? i + 1 : last;
        int i2 = i + 2 <= last ? i + 2 : last;
        int i3 = i + 3 <= last ? i + 3 : last;
        int s0 = csr[i], s1 = csr[i1], s2 = csr[i2], s3 = csr[i3];
        float2 v0 = *(const float2*)&Hs[(size_t)s0 * CH + c];
        float2 v1 = *(const float2*)&Hs[(size_t)s1 * CH + c];
        float2 v2 = *(const float2*)&Hs[(size_t)s2 * CH + c];
        float2 v3 = *(const float2*)&Hs[(size_t)s3 * CH + c];
        float m1 = (i + 1 < end) ? 1.f : 0.f;
        float m2 = (i + 2 < end) ? 1.f : 0.f;
        float m3 = (i + 3 < end) ? 1.f : 0.f;
        acc.x += v0.x + m1 * v1.x + (m2 * v2.x + m3 * v3.x);
        acc.y += v0.y + m1 * v1.y + (m2 * v2.y + m3 * v3.y);
    }
    float d = dis[dst];
    float2 b = *(const float2*)&bias[c];
    float o0 = fmaf(acc.x, d, b.x);
    float o1 = fmaf(acc.y, d, b.y);
    if (relu) { o0 = fmaxf(o0, 0.f); o1 = fmaxf(o1, 0.f); }
    *(float2*)&out[(size_t)dst * CH + c] = make_float2(o0, o1);
}

// ---------------- layer 3 transform (128 -> 2): wave per row ----------------
__global__ __launch_bounds__(256) void gemm_out_kernel(
    const float* __restrict__ H, const float* __restrict__ W3,
    const float* __restrict__ dis, float* __restrict__ H3, int n) {
    int row = blockIdx.x * 4 + (threadIdx.x >> 6);
    int lane = threadIdx.x & 63;
    if (row >= n) return;
    float2 v = *(const float2*)&H[(size_t)row * CH + lane * 2];
    float4 w = *(const float4*)&W3[lane * 4];
    float a0 = v.x * w.x + v.y * w.z;
    float a1 = v.x * w.y + v.y * w.w;
    #pragma unroll
    for (int off = 32; off > 0; off >>= 1) {
        a0 += __shfl_xor(a0, off, 64);
        a1 += __shfl_xor(a1, off, 64);
    }
    if (lane == 0) {
        float d = dis[row];
        H3[row * 2]     = a0 * d;
        H3[row * 2 + 1] = a1 * d;
    }
}

// ---------------- layer 3 aggregation (2 ch): thread per dst, 4-deep ----------------
__global__ void agg_out_kernel(const float* __restrict__ H3, const int* __restrict__ rs,
                               const int* __restrict__ csr, const float* __restrict__ dis,
                               const float* __restrict__ b3, float* __restrict__ out, int n) {
    int dst = blockIdx.x * blockDim.x + threadIdx.x;
    if (dst >= n) return;
    float2 acc = *(const float2*)&H3[dst * 2];
    int beg = rs[dst], end = rs[dst + 1];
    int last = end - 1;
    for (int i = beg; i < end; i += 4) {
        int i1 = i + 1 <= last ? i + 1 : last;
        int i2 = i + 2 <= last ? i + 2 : last;
        int i3 = i + 3 <= last ? i + 3 : last;
        int s0 = csr[i], s1 = csr[i1], s2 = csr[i2], s3 = csr[i3];
        float2 v0 = *(const float2*)&H3[s0 * 2];
        float2 v1 = *(const float2*)&H3[s1 * 2];
        float2 v2 = *(const float2*)&H3[s2 * 2];
        float2 v3 = *(const float2*)&H3[s3 * 2];
        float m1 = (i + 1 < end) ? 1.f : 0.f;
        float m2 = (i + 2 < end) ? 1.f : 0.f;
        float m3 = (i + 3 < end) ? 1.f : 0.f;
        acc.x += v0.x + m1 * v1.x + (m2 * v2.x + m3 * v3.x);
        acc.y += v0.y + m1 * v1.y + (m2 * v2.y + m3 * v3.y);
    }
    float d = dis[dst];
    out[dst * 2]     = fmaf(acc.x, d, b3[0]);
    out[dst * 2 + 1] = fmaf(acc.y, d, b3[1]);
}

extern "C" void kernel_launch(void* const* d_in, const int* in_sizes, int n_in,
                              void* d_out, int out_size, void* d_ws, size_t ws_size,
                              hipStream_t stream) {
    const float* x  = (const float*)d_in[0];
    const void*  ei = d_in[1];
    const float* W1 = (const float*)d_in[2];
    const float* b1 = (const float*)d_in[3];
    const float* W2 = (const float*)d_in[4];
    const float* b2 = (const float*)d_in[5];
    const float* W3 = (const float*)d_in[6];
    const float* b3 = (const float*)d_in[7];
    float* out = (float*)d_out;

    const int n = in_sizes[0] / CH;      // 100000
    const int e = in_sizes[1] / 2;       // 1600000

    char* w = (char*)d_ws;
    size_t off = 0;
    auto alloc = [&](size_t bytes) { char* p = w + off; off = (off + bytes + 255) & ~(size_t)255; return p; };
    float* bufA   = (float*)alloc((size_t)n * CH * 4);
    float* bufB   = (float*)alloc((size_t)n * CH * 4);
    int*   csr    = (int*)  alloc((size_t)e * 4);
    float* dis    = (float*)alloc((size_t)n * 4);
    int*   rs     = (int*)  alloc(((size_t)n + 1) * 4);
    float* H3     = (float*)alloc((size_t)n * 2 * 4);
    int*   bsum   = (int*)  alloc(1024 * 4);
    char* zbase   = w + off;
    int*   cnt    = (int*)  alloc((size_t)n * 4);
    int*   cursor = (int*)  alloc((size_t)n * 4);
    int*   flag   = (int*)  alloc(256);
    size_t zbytes = (size_t)((w + off) - zbase);

    hipMemsetAsync(zbase, 0, zbytes, stream);

    detect_kernel<<<8, 1024, 0, stream>>>((const int*)ei, flag, 2 * e);
    count_kernel<<<(e + 255) / 256, 256, 0, stream>>>(ei, flag, cnt, e);

    const int nb = (n + 255) / 256;
    scan_pass1<<<nb, 256, 0, stream>>>(cnt, bsum, n);
    scan_pass2<<<1, 1024, 0, stream>>>(bsum, nb);
    scan_pass3<<<nb, 256, 0, stream>>>(cnt, bsum, rs, dis, n, e);

    scatter_kernel<<<(e + 255) / 256, 256, 0, stream>>>(ei, flag, rs, cursor, csr, e);

    const int gemmGrid = (n + 63) / 64;
    const int aggGrid  = (n + 3) / 4;

    gemm128_kernel<<<gemmGrid, 256, 0, stream>>>(x, W1, dis, bufA, n);
    agg128_kernel<<<aggGrid, 256, 0, stream>>>(bufA, rs, csr, dis, b1, bufB, n, 1);
    gemm128_kernel<<<gemmGrid, 256, 0, stream>>>(bufB, W2, dis, bufA, n);
    agg128_kernel<<<aggGrid, 256, 0, stream>>>(bufA, rs, csr, dis, b2, bufB, n, 1);
    gemm_out_kernel<<<aggGrid, 256, 0, stream>>>(bufB, W3, dis, H3, n);
    agg_out_kernel<<<(n + 255) / 256, 256, 0, stream>>>(H3, rs, csr, dis, b3, out, n);
}

// Round 4
// 495.992 us; speedup vs baseline: 1.8777x; 1.3021x over previous
//
#include <hip/hip_runtime.h>

#define CH 128

typedef float f32x4 __attribute__((ext_vector_type(4)));
typedef short s16x8 __attribute__((ext_vector_type(8)));

// ---------------- edge dtype detection (int32 vs int64) ----------------
__global__ void detect_kernel(const int* __restrict__ ei, int* __restrict__ flag, int nwords) {
    int i = blockIdx.x * blockDim.x + threadIdx.x;
    int w = 2 * i + 1;
    if (w < nwords) {
        if (ei[w] != 0) atomicOr(flag, 1);
    }
}

__device__ __forceinline__ int edge_at(const void* ei, int idx, int is64) {
    if (is64) return (int)((const long long*)ei)[idx];
    return ((const int*)ei)[idx];
}

// ---------------- degree count ----------------
__global__ void count_kernel(const void* __restrict__ ei, const int* __restrict__ flag,
                             int* __restrict__ cnt, int e) {
    int i = blockIdx.x * blockDim.x + threadIdx.x;
    if (i < e) {
        int is64 = (*flag == 0);
        int d = edge_at(ei, e + i, is64);
        atomicAdd(&cnt[d], 1);
    }
}

// ---------------- multi-block exclusive scan over cnt -> rs ----------------
__global__ __launch_bounds__(256) void scan_pass1(const int* __restrict__ cnt,
                                                  int* __restrict__ bsum, int n) {
    __shared__ int s[256];
    int i = blockIdx.x * 256 + threadIdx.x;
    s[threadIdx.x] = (i < n) ? cnt[i] : 0;
    __syncthreads();
    #pragma unroll
    for (int off = 128; off > 0; off >>= 1) {
        if (threadIdx.x < off) s[threadIdx.x] += s[threadIdx.x + off];
        __syncthreads();
    }
    if (threadIdx.x == 0) bsum[blockIdx.x] = s[0];
}

__global__ __launch_bounds__(1024) void scan_pass2(int* __restrict__ bsum, int nb) {
    __shared__ int s[1024];
    int tid = threadIdx.x;
    int v = (tid < nb) ? bsum[tid] : 0;
    s[tid] = v;
    __syncthreads();
    for (int off = 1; off < 1024; off <<= 1) {
        int t = (tid >= off) ? s[tid - off] : 0;
        __syncthreads();
        s[tid] += t;
        __syncthreads();
    }
    if (tid < nb) bsum[tid] = s[tid] - v;   // exclusive
}

__global__ __launch_bounds__(256) void scan_pass3(const int* __restrict__ cnt,
                                                  const int* __restrict__ bsum,
                                                  int* __restrict__ rs,
                                                  float* __restrict__ dis, int n, int e) {
    __shared__ int s[256];
    int i = blockIdx.x * 256 + threadIdx.x;
    int v = (i < n) ? cnt[i] : 0;
    s[threadIdx.x] = v;
    __syncthreads();
    #pragma unroll
    for (int off = 1; off < 256; off <<= 1) {
        int t = (threadIdx.x >= off) ? s[threadIdx.x - off] : 0;
        __syncthreads();
        s[threadIdx.x] += t;
        __syncthreads();
    }
    if (i < n) {
        rs[i] = s[threadIdx.x] - v + bsum[blockIdx.x];
        dis[i] = rsqrtf((float)v + 1.0f);
        if (i == n - 1) rs[n] = e;
    }
}

// ---------------- CSR scatter ----------------
__global__ void scatter_kernel(const void* __restrict__ ei, const int* __restrict__ flag,
                               const int* __restrict__ rs, int* __restrict__ cursor,
                               int* __restrict__ csr, int e) {
    int i = blockIdx.x * blockDim.x + threadIdx.x;
    if (i < e) {
        int is64 = (*flag == 0);
        int s = edge_at(ei, i, is64);
        int d = edge_at(ei, e + i, is64);
        int pos = rs[d] + atomicAdd(&cursor[d], 1);
        csr[pos] = s;
    }
}

// ---------------- W split+transpose: W[k][c] fp32 -> WhT/WlT[c][k] bf16 ----------------
__global__ void wsplit_kernel(const float* __restrict__ W, unsigned short* __restrict__ WhT,
                              unsigned short* __restrict__ WlT) {
    int idx = blockIdx.x * 256 + threadIdx.x;   // 0..16383
    int k = idx >> 7, c = idx & 127;
    float w = W[idx];
    unsigned int u = __float_as_uint(w);
    unsigned short hi = (unsigned short)(u >> 16);
    float rem = w - __uint_as_float((unsigned int)hi << 16);
    unsigned short lo = (unsigned short)(__float_as_uint(rem) >> 16);
    WhT[c * 128 + k] = hi;
    WlT[c * 128 + k] = lo;
}

// ---------------- split-bf16 MFMA GEMM: out[r][c] = dis[r] * sum_k X[r][k] W[k][c] ----------------
// block = 256 thr (4 waves), tile = 128 rows x 128 cols. W (hi/lo, transposed) staged in
// 64KB LDS with XOR swizzle; A fragments read from global fp32 and split in registers.
__device__ __forceinline__ void split8(float4 a0, float4 a1, s16x8& h, s16x8& l) {
    float v[8] = {a0.x, a0.y, a0.z, a0.w, a1.x, a1.y, a1.z, a1.w};
    #pragma unroll
    for (int j = 0; j < 8; ++j) {
        unsigned int u = __float_as_uint(v[j]);
        unsigned short hi = (unsigned short)(u >> 16);
        float rem = v[j] - __uint_as_float((unsigned int)hi << 16);
        h[j] = (short)hi;
        l[j] = (short)(__float_as_uint(rem) >> 16);
    }
}

__global__ __launch_bounds__(256) void gemm_mfma_kernel(
    const float* __restrict__ X, const unsigned short* __restrict__ WhT,
    const unsigned short* __restrict__ WlT, const float* __restrict__ dis,
    float* __restrict__ out, int n) {
    __shared__ unsigned short bsh[128 * 128];   // [col][k] bf16 hi, swizzled
    __shared__ unsigned short bsl[128 * 128];   // [col][k] bf16 lo, swizzled
    const int tid = threadIdx.x;

    // stage W: 2048 16B-chunks per array
    #pragma unroll
    for (int it = 0; it < 8; ++it) {
        int idx = it * 256 + tid;               // chunk id
        int col = idx >> 4;
        int ch  = idx & 15;
        int byte = (col * 256 + ch * 16) ^ ((col & 7) << 4);
        *(uint4*)((char*)bsh + byte) = ((const uint4*)WhT)[idx];
        *(uint4*)((char*)bsl + byte) = ((const uint4*)WlT)[idx];
    }
    __syncthreads();

    const int lane = tid & 63;
    const int wv = tid >> 6;
    const int rbase = blockIdx.x * 128 + wv * 32;
    const int lr = lane & 15;       // row/col offset within fragment
    const int lg = lane >> 4;       // lane group 0..3

    f32x4 acc[2][8];
    #pragma unroll
    for (int rt = 0; rt < 2; ++rt)
        #pragma unroll
        for (int ct = 0; ct < 8; ++ct) acc[rt][ct] = (f32x4)0.f;

    #pragma unroll
    for (int kk = 0; kk < 4; ++kk) {
        const int k0 = kk * 32 + lg * 8;
        // B fragments from LDS
        s16x8 bh[8], bl[8];
        #pragma unroll
        for (int ct = 0; ct < 8; ++ct) {
            int col = ct * 16 + lr;
            int byte = (col * 256 + k0 * 2) ^ ((col & 7) << 4);
            bh[ct] = *(const s16x8*)((const char*)bsh + byte);
            bl[ct] = *(const s16x8*)((const char*)bsl + byte);
        }
        // A fragments from global + MFMA
        #pragma unroll
        for (int rt = 0; rt < 2; ++rt) {
            int row = rbase + rt * 16 + lr;
            float4 a0 = make_float4(0.f, 0.f, 0.f, 0.f);
            float4 a1 = make_float4(0.f, 0.f, 0.f, 0.f);
            if (row < n) {
                a0 = *(const float4*)&X[(size_t)row * CH + k0];
                a1 = *(const float4*)&X[(size_t)row * CH + k0 + 4];
            }
            s16x8 ah, al;
            split8(a0, a1, ah, al);
            #pragma unroll
            for (int ct = 0; ct < 8; ++ct) {
                acc[rt][ct] = __builtin_amdgcn_mfma_f32_16x16x32_bf16(ah, bh[ct], acc[rt][ct], 0, 0, 0);
                acc[rt][ct] = __builtin_amdgcn_mfma_f32_16x16x32_bf16(al, bh[ct], acc[rt][ct], 0, 0, 0);
                acc[rt][ct] = __builtin_amdgcn_mfma_f32_16x16x32_bf16(ah, bl[ct], acc[rt][ct], 0, 0, 0);
            }
        }
    }

    // epilogue: D row = (lane>>4)*4 + reg, col = lane&15 within each 16x16 tile
    #pragma unroll
    for (int rt = 0; rt < 2; ++rt) {
        #pragma unroll
        for (int reg = 0; reg < 4; ++reg) {
            int row = rbase + rt * 16 + lg * 4 + reg;
            if (row < n) {
                float d = dis[row];
                #pragma unroll
                for (int ct = 0; ct < 8; ++ct) {
                    int col = ct * 16 + lr;
                    out[(size_t)row * CH + col] = acc[rt][ct][reg] * d;
                }
            }
        }
    }
}

// ---------------- aggregation (128 ch): wave per dst, 4-deep MLP unroll ----------------
__global__ __launch_bounds__(256) void agg128_kernel(
    const float* __restrict__ Hs, const int* __restrict__ rs, const int* __restrict__ csr,
    const float* __restrict__ dis, const float* __restrict__ bias,
    float* __restrict__ out, int n, int relu) {
    int dst = blockIdx.x * 4 + (threadIdx.x >> 6);
    if (dst >= n) return;
    int lane = threadIdx.x & 63;
    int c = lane * 2;
    float2 acc = *(const float2*)&Hs[(size_t)dst * CH + c];  // self term
    int beg = rs[dst], end = rs[dst + 1];
    int last = end - 1;
    for (int i = beg; i < end; i += 4) {
        int i1 = i + 1 <= last ? i + 1 : last;
        int i2 = i + 2 <= last ? i + 2 : last;
        int i3 = i + 3 <= last ? i + 3 : last;
        int s0 = csr[i], s1 = csr[i1], s2 = csr[i2], s3 = csr[i3];
        float2 v0 = *(const float2*)&Hs[(size_t)s0 * CH + c];
        float2 v1 = *(const float2*)&Hs[(size_t)s1 * CH + c];
        float2 v2 = *(const float2*)&Hs[(size_t)s2 * CH + c];
        float2 v3 = *(const float2*)&Hs[(size_t)s3 * CH + c];
        float m1 = (i + 1 < end) ? 1.f : 0.f;
        float m2 = (i + 2 < end) ? 1.f : 0.f;
        float m3 = (i + 3 < end) ? 1.f : 0.f;
        acc.x += v0.x + m1 * v1.x + (m2 * v2.x + m3 * v3.x);
        acc.y += v0.y + m1 * v1.y + (m2 * v2.y + m3 * v3.y);
    }
    float d = dis[dst];
    float2 b = *(const float2*)&bias[c];
    float o0 = fmaf(acc.x, d, b.x);
    float o1 = fmaf(acc.y, d, b.y);
    if (relu) { o0 = fmaxf(o0, 0.f); o1 = fmaxf(o1, 0.f); }
    *(float2*)&out[(size_t)dst * CH + c] = make_float2(o0, o1);
}

// ---------------- layer 3 transform (128 -> 2): wave per row ----------------
__global__ __launch_bounds__(256) void gemm_out_kernel(
    const float* __restrict__ H, const float* __restrict__ W3,
    const float* __restrict__ dis, float* __restrict__ H3, int n) {
    int row = blockIdx.x * 4 + (threadIdx.x >> 6);
    int lane = threadIdx.x & 63;
    if (row >= n) return;
    float2 v = *(const float2*)&H[(size_t)row * CH + lane * 2];
    float4 w = *(const float4*)&W3[lane * 4];
    float a0 = v.x * w.x + v.y * w.z;
    float a1 = v.x * w.y + v.y * w.w;
    #pragma unroll
    for (int off = 32; off > 0; off >>= 1) {
        a0 += __shfl_xor(a0, off, 64);
        a1 += __shfl_xor(a1, off, 64);
    }
    if (lane == 0) {
        float d = dis[row];
        H3[row * 2]     = a0 * d;
        H3[row * 2 + 1] = a1 * d;
    }
}

// ---------------- layer 3 aggregation (2 ch): thread per dst, 4-deep ----------------
__global__ void agg_out_kernel(const float* __restrict__ H3, const int* __restrict__ rs,
                               const int* __restrict__ csr, const float* __restrict__ dis,
                               const float* __restrict__ b3, float* __restrict__ out, int n) {
    int dst = blockIdx.x * blockDim.x + threadIdx.x;
    if (dst >= n) return;
    float2 acc = *(const float2*)&H3[dst * 2];
    int beg = rs[dst], end = rs[dst + 1];
    int last = end - 1;
    for (int i = beg; i < end; i += 4) {
        int i1 = i + 1 <= last ? i + 1 : last;
        int i2 = i + 2 <= last ? i + 2 : last;
        int i3 = i + 3 <= last ? i + 3 : last;
        int s0 = csr[i], s1 = csr[i1], s2 = csr[i2], s3 = csr[i3];
        float2 v0 = *(const float2*)&H3[s0 * 2];
        float2 v1 = *(const float2*)&H3[s1 * 2];
        float2 v2 = *(const float2*)&H3[s2 * 2];
        float2 v3 = *(const float2*)&H3[s3 * 2];
        float m1 = (i + 1 < end) ? 1.f : 0.f;
        float m2 = (i + 2 < end) ? 1.f : 0.f;
        float m3 = (i + 3 < end) ? 1.f : 0.f;
        acc.x += v0.x + m1 * v1.x + (m2 * v2.x + m3 * v3.x);
        acc.y += v0.y + m1 * v1.y + (m2 * v2.y + m3 * v3.y);
    }
    float d = dis[dst];
    out[dst * 2]     = fmaf(acc.x, d, b3[0]);
    out[dst * 2 + 1] = fmaf(acc.y, d, b3[1]);
}

extern "C" void kernel_launch(void* const* d_in, const int* in_sizes, int n_in,
                              void* d_out, int out_size, void* d_ws, size_t ws_size,
                              hipStream_t stream) {
    const float* x  = (const float*)d_in[0];
    const void*  ei = d_in[1];
    const float* W1 = (const float*)d_in[2];
    const float* b1 = (const float*)d_in[3];
    const float* W2 = (const float*)d_in[4];
    const float* b2 = (const float*)d_in[5];
    const float* W3 = (const float*)d_in[6];
    const float* b3 = (const float*)d_in[7];
    float* out = (float*)d_out;

    const int n = in_sizes[0] / CH;      // 100000
    const int e = in_sizes[1] / 2;       // 1600000

    char* w = (char*)d_ws;
    size_t off = 0;
    auto alloc = [&](size_t bytes) { char* p = w + off; off = (off + bytes + 255) & ~(size_t)255; return p; };
    float* bufA   = (float*)alloc((size_t)n * CH * 4);
    float* bufB   = (float*)alloc((size_t)n * CH * 4);
    int*   csr    = (int*)  alloc((size_t)e * 4);
    float* dis    = (float*)alloc((size_t)n * 4);
    int*   rs     = (int*)  alloc(((size_t)n + 1) * 4);
    float* H3     = (float*)alloc((size_t)n * 2 * 4);
    int*   bsum   = (int*)  alloc(1024 * 4);
    unsigned short* WhT = (unsigned short*)alloc(128 * 128 * 2);
    unsigned short* WlT = (unsigned short*)alloc(128 * 128 * 2);
    char* zbase   = w + off;
    int*   cnt    = (int*)  alloc((size_t)n * 4);
    int*   cursor = (int*)  alloc((size_t)n * 4);
    int*   flag   = (int*)  alloc(256);
    size_t zbytes = (size_t)((w + off) - zbase);

    hipMemsetAsync(zbase, 0, zbytes, stream);

    detect_kernel<<<8, 1024, 0, stream>>>((const int*)ei, flag, 2 * e);
    count_kernel<<<(e + 255) / 256, 256, 0, stream>>>(ei, flag, cnt, e);

    const int nb = (n + 255) / 256;
    scan_pass1<<<nb, 256, 0, stream>>>(cnt, bsum, n);
    scan_pass2<<<1, 1024, 0, stream>>>(bsum, nb);
    scan_pass3<<<nb, 256, 0, stream>>>(cnt, bsum, rs, dis, n, e);

    scatter_kernel<<<(e + 255) / 256, 256, 0, stream>>>(ei, flag, rs, cursor, csr, e);

    const int mfmaGrid = (n + 127) / 128;
    const int aggGrid  = (n + 3) / 4;

    // layer 1
    wsplit_kernel<<<64, 256, 0, stream>>>(W1, WhT, WlT);
    gemm_mfma_kernel<<<mfmaGrid, 256, 0, stream>>>(x, WhT, WlT, dis, bufA, n);
    agg128_kernel<<<aggGrid, 256, 0, stream>>>(bufA, rs, csr, dis, b1, bufB, n, 1);
    // layer 2
    wsplit_kernel<<<64, 256, 0, stream>>>(W2, WhT, WlT);
    gemm_mfma_kernel<<<mfmaGrid, 256, 0, stream>>>(bufB, WhT, WlT, dis, bufA, n);
    agg128_kernel<<<aggGrid, 256, 0, stream>>>(bufA, rs, csr, dis, b2, bufB, n, 1);
    // layer 3
    gemm_out_kernel<<<aggGrid, 256, 0, stream>>>(bufB, W3, dis, H3, n);
    agg_out_kernel<<<(n + 255) / 256, 256, 0, stream>>>(H3, rs, csr, dis, b3, out, n);
}

// Round 5
// 431.592 us; speedup vs baseline: 2.1579x; 1.1492x over previous
//
#include <hip/hip_runtime.h>

#define CH 128
#define BCHUNK 4096   // edges per binning block (16 per thread @ 256 thr)
#define NB 256        // max buckets

typedef float f32x4 __attribute__((ext_vector_type(4)));
typedef short s16x8 __attribute__((ext_vector_type(8)));

// ---------------- edge dtype detection (int32 vs int64) ----------------
__global__ void detect_kernel(const int* __restrict__ ei, int* __restrict__ flag, int nwords) {
    int i = blockIdx.x * blockDim.x + threadIdx.x;
    int w = 2 * i + 1;
    if (w < nwords) {
        if (ei[w] != 0) atomicOr(flag, 1);
    }
}

__device__ __forceinline__ int edge_at(const void* ei, int idx, int is64) {
    if (is64) return (int)((const long long*)ei)[idx];
    return ((const int*)ei)[idx];
}

// ---------------- CSR build pass A: histogram / scans / bin ----------------
__global__ __launch_bounds__(256) void hist_kernel(const void* __restrict__ ei,
                                                   const int* __restrict__ flag,
                                                   int* __restrict__ hist, int e, int shift) {
    __shared__ int h[NB];
    h[threadIdx.x] = 0;
    __syncthreads();
    int is64 = (*flag == 0);
    int base = blockIdx.x * BCHUNK;
    #pragma unroll
    for (int k = 0; k < BCHUNK / 256; ++k) {
        int i = base + k * 256 + threadIdx.x;
        if (i < e) {
            int d = edge_at(ei, e + i, is64);
            atomicAdd(&h[d >> shift], 1);
        }
    }
    __syncthreads();
    hist[blockIdx.x * NB + threadIdx.x] = h[threadIdx.x];
}

// per-bucket exclusive scan over blocks (column scan); also bucket totals
__global__ __launch_bounds__(512) void scan_col_kernel(int* __restrict__ hist,
                                                       int* __restrict__ btot, int nblk) {
    __shared__ int s[512];
    int b = blockIdx.x;
    int tid = threadIdx.x;
    int v = (tid < nblk) ? hist[tid * NB + b] : 0;
    s[tid] = v;
    __syncthreads();
    for (int off = 1; off < 512; off <<= 1) {
        int t = (tid >= off) ? s[tid - off] : 0;
        __syncthreads();
        s[tid] += t;
        __syncthreads();
    }
    if (tid < nblk) hist[tid * NB + b] = s[tid] - v;   // exclusive
    if (tid == 511) btot[b] = s[511];
}

__global__ __launch_bounds__(NB) void scan_btot_kernel(const int* __restrict__ btot,
                                                       int* __restrict__ bstart) {
    __shared__ int s[NB];
    int tid = threadIdx.x;
    int v = btot[tid];
    s[tid] = v;
    __syncthreads();
    for (int off = 1; off < NB; off <<= 1) {
        int t = (tid >= off) ? s[tid - off] : 0;
        __syncthreads();
        s[tid] += t;
        __syncthreads();
    }
    bstart[tid] = s[tid] - v;
    if (tid == NB - 1) bstart[NB] = s[NB - 1];
}

__global__ __launch_bounds__(256) void bin_kernel(const void* __restrict__ ei,
                                                  const int* __restrict__ flag,
                                                  const int* __restrict__ hist,
                                                  const int* __restrict__ bstart,
                                                  int2* __restrict__ binned, int e, int shift) {
    __shared__ int c[NB];
    c[threadIdx.x] = 0;
    __syncthreads();
    int is64 = (*flag == 0);
    int base = blockIdx.x * BCHUNK;
    #pragma unroll
    for (int k = 0; k < BCHUNK / 256; ++k) {
        int i = base + k * 256 + threadIdx.x;
        if (i < e) {
            int sN = edge_at(ei, i, is64);
            int d  = edge_at(ei, e + i, is64);
            int b  = d >> shift;
            int r  = atomicAdd(&c[b], 1);
            int pos = bstart[b] + hist[blockIdx.x * NB + b] + r;
            binned[pos] = make_int2(sN, d);
        }
    }
}

// ---------------- CSR build pass B: bucket-owned count + scatter ----------------
__global__ __launch_bounds__(256) void count_binned_kernel(const int2* __restrict__ binned,
                                                           const int* __restrict__ bstart,
                                                           int* __restrict__ cnt) {
    int b = blockIdx.x;
    int beg = bstart[b], end = bstart[b + 1];
    for (int i = beg + threadIdx.x; i < end; i += 256)
        atomicAdd(&cnt[binned[i].y], 1);
}

__global__ __launch_bounds__(256) void scatter2_kernel(const int2* __restrict__ binned,
                                                       const int* __restrict__ bstart,
                                                       const int* __restrict__ rs,
                                                       int* __restrict__ cursor,
                                                       int* __restrict__ csr) {
    int b = blockIdx.x;
    int beg = bstart[b], end = bstart[b + 1];
    for (int i = beg + threadIdx.x; i < end; i += 256) {
        int2 p = binned[i];
        int pos = rs[p.y] + atomicAdd(&cursor[p.y], 1);
        csr[pos] = p.x;
    }
}

// ---------------- multi-block exclusive scan over cnt -> rs ----------------
__global__ __launch_bounds__(256) void scan_pass1(const int* __restrict__ cnt,
                                                  int* __restrict__ bsum, int n) {
    __shared__ int s[256];
    int i = blockIdx.x * 256 + threadIdx.x;
    s[threadIdx.x] = (i < n) ? cnt[i] : 0;
    __syncthreads();
    #pragma unroll
    for (int off = 128; off > 0; off >>= 1) {
        if (threadIdx.x < off) s[threadIdx.x] += s[threadIdx.x + off];
        __syncthreads();
    }
    if (threadIdx.x == 0) bsum[blockIdx.x] = s[0];
}

__global__ __launch_bounds__(1024) void scan_pass2(int* __restrict__ bsum, int nb) {
    __shared__ int s[1024];
    int tid = threadIdx.x;
    int v = (tid < nb) ? bsum[tid] : 0;
    s[tid] = v;
    __syncthreads();
    for (int off = 1; off < 1024; off <<= 1) {
        int t = (tid >= off) ? s[tid - off] : 0;
        __syncthreads();
        s[tid] += t;
        __syncthreads();
    }
    if (tid < nb) bsum[tid] = s[tid] - v;   // exclusive
}

__global__ __launch_bounds__(256) void scan_pass3(const int* __restrict__ cnt,
                                                  const int* __restrict__ bsum,
                                                  int* __restrict__ rs,
                                                  float* __restrict__ dis, int n, int e) {
    __shared__ int s[256];
    int i = blockIdx.x * 256 + threadIdx.x;
    int v = (i < n) ? cnt[i] : 0;
    s[threadIdx.x] = v;
    __syncthreads();
    #pragma unroll
    for (int off = 1; off < 256; off <<= 1) {
        int t = (threadIdx.x >= off) ? s[threadIdx.x - off] : 0;
        __syncthreads();
        s[threadIdx.x] += t;
        __syncthreads();
    }
    if (i < n) {
        rs[i] = s[threadIdx.x] - v + bsum[blockIdx.x];
        dis[i] = rsqrtf((float)v + 1.0f);
        if (i == n - 1) rs[n] = e;
    }
}

// ---------------- W split+transpose: W[k][c] fp32 -> WhT/WlT[c][k] bf16 ----------------
__global__ void wsplit_kernel(const float* __restrict__ W, unsigned short* __restrict__ WhT,
                              unsigned short* __restrict__ WlT) {
    int idx = blockIdx.x * 256 + threadIdx.x;   // 0..16383
    int k = idx >> 7, c = idx & 127;
    float w = W[idx];
    unsigned int u = __float_as_uint(w);
    unsigned short hi = (unsigned short)(u >> 16);
    float rem = w - __uint_as_float((unsigned int)hi << 16);
    unsigned short lo = (unsigned short)(__float_as_uint(rem) >> 16);
    WhT[c * 128 + k] = hi;
    WlT[c * 128 + k] = lo;
}

// ---------------- split-bf16 MFMA GEMM ----------------
__device__ __forceinline__ void split8(float4 a0, float4 a1, s16x8& h, s16x8& l) {
    float v[8] = {a0.x, a0.y, a0.z, a0.w, a1.x, a1.y, a1.z, a1.w};
    #pragma unroll
    for (int j = 0; j < 8; ++j) {
        unsigned int u = __float_as_uint(v[j]);
        unsigned short hi = (unsigned short)(u >> 16);
        float rem = v[j] - __uint_as_float((unsigned int)hi << 16);
        h[j] = (short)hi;
        l[j] = (short)(__float_as_uint(rem) >> 16);
    }
}

__global__ __launch_bounds__(256) void gemm_mfma_kernel(
    const float* __restrict__ X, const unsigned short* __restrict__ WhT,
    const unsigned short* __restrict__ WlT, const float* __restrict__ dis,
    float* __restrict__ out, int n) {
    __shared__ unsigned short bsh[128 * 128];   // [col][k] bf16 hi, swizzled
    __shared__ unsigned short bsl[128 * 128];   // [col][k] bf16 lo, swizzled
    const int tid = threadIdx.x;

    #pragma unroll
    for (int it = 0; it < 8; ++it) {
        int idx = it * 256 + tid;
        int col = idx >> 4;
        int ch  = idx & 15;
        int byte = (col * 256 + ch * 16) ^ ((col & 7) << 4);
        *(uint4*)((char*)bsh + byte) = ((const uint4*)WhT)[idx];
        *(uint4*)((char*)bsl + byte) = ((const uint4*)WlT)[idx];
    }
    __syncthreads();

    const int lane = tid & 63;
    const int wv = tid >> 6;
    const int rbase = blockIdx.x * 128 + wv * 32;
    const int lr = lane & 15;
    const int lg = lane >> 4;

    f32x4 acc[2][8];
    #pragma unroll
    for (int rt = 0; rt < 2; ++rt)
        #pragma unroll
        for (int ct = 0; ct < 8; ++ct) acc[rt][ct] = (f32x4)0.f;

    #pragma unroll
    for (int kk = 0; kk < 4; ++kk) {
        const int k0 = kk * 32 + lg * 8;
        s16x8 bh[8], bl[8];
        #pragma unroll
        for (int ct = 0; ct < 8; ++ct) {
            int col = ct * 16 + lr;
            int byte = (col * 256 + k0 * 2) ^ ((col & 7) << 4);
            bh[ct] = *(const s16x8*)((const char*)bsh + byte);
            bl[ct] = *(const s16x8*)((const char*)bsl + byte);
        }
        #pragma unroll
        for (int rt = 0; rt < 2; ++rt) {
            int row = rbase + rt * 16 + lr;
            float4 a0 = make_float4(0.f, 0.f, 0.f, 0.f);
            float4 a1 = make_float4(0.f, 0.f, 0.f, 0.f);
            if (row < n) {
                a0 = *(const float4*)&X[(size_t)row * CH + k0];
                a1 = *(const float4*)&X[(size_t)row * CH + k0 + 4];
            }
            s16x8 ah, al;
            split8(a0, a1, ah, al);
            #pragma unroll
            for (int ct = 0; ct < 8; ++ct) {
                acc[rt][ct] = __builtin_amdgcn_mfma_f32_16x16x32_bf16(ah, bh[ct], acc[rt][ct], 0, 0, 0);
                acc[rt][ct] = __builtin_amdgcn_mfma_f32_16x16x32_bf16(al, bh[ct], acc[rt][ct], 0, 0, 0);
                acc[rt][ct] = __builtin_amdgcn_mfma_f32_16x16x32_bf16(ah, bl[ct], acc[rt][ct], 0, 0, 0);
            }
        }
    }

    #pragma unroll
    for (int rt = 0; rt < 2; ++rt) {
        #pragma unroll
        for (int reg = 0; reg < 4; ++reg) {
            int row = rbase + rt * 16 + lg * 4 + reg;
            if (row < n) {
                float d = dis[row];
                #pragma unroll
                for (int ct = 0; ct < 8; ++ct) {
                    int col = ct * 16 + lr;
                    out[(size_t)row * CH + col] = acc[rt][ct][reg] * d;
                }
            }
        }
    }
}

// ---------------- aggregation (128 ch): wave per dst, 4-deep MLP unroll ----------------
__global__ __launch_bounds__(256) void agg128_kernel(
    const float* __restrict__ Hs, const int* __restrict__ rs, const int* __restrict__ csr,
    const float* __restrict__ dis, const float* __restrict__ bias,
    float* __restrict__ out, int n, int relu) {
    int dst = blockIdx.x * 4 + (threadIdx.x >> 6);
    if (dst >= n) return;
    int lane = threadIdx.x & 63;
    int c = lane * 2;
    float2 acc = *(const float2*)&Hs[(size_t)dst * CH + c];
    int beg = rs[dst], end = rs[dst + 1];
    int last = end - 1;
    for (int i = beg; i < end; i += 4) {
        int i1 = i + 1 <= last ? i + 1 : last;
        int i2 = i + 2 <= last ? i + 2 : last;
        int i3 = i + 3 <= last ? i + 3 : last;
        int s0 = csr[i], s1 = csr[i1], s2 = csr[i2], s3 = csr[i3];
        float2 v0 = *(const float2*)&Hs[(size_t)s0 * CH + c];
        float2 v1 = *(const float2*)&Hs[(size_t)s1 * CH + c];
        float2 v2 = *(const float2*)&Hs[(size_t)s2 * CH + c];
        float2 v3 = *(const float2*)&Hs[(size_t)s3 * CH + c];
        float m1 = (i + 1 < end) ? 1.f : 0.f;
        float m2 = (i + 2 < end) ? 1.f : 0.f;
        float m3 = (i + 3 < end) ? 1.f : 0.f;
        acc.x += v0.x + m1 * v1.x + (m2 * v2.x + m3 * v3.x);
        acc.y += v0.y + m1 * v1.y + (m2 * v2.y + m3 * v3.y);
    }
    float d = dis[dst];
    float2 b = *(const float2*)&bias[c];
    float o0 = fmaf(acc.x, d, b.x);
    float o1 = fmaf(acc.y, d, b.y);
    if (relu) { o0 = fmaxf(o0, 0.f); o1 = fmaxf(o1, 0.f); }
    *(float2*)&out[(size_t)dst * CH + c] = make_float2(o0, o1);
}

// ---------------- layer 3 transform (128 -> 2): wave per row ----------------
__global__ __launch_bounds__(256) void gemm_out_kernel(
    const float* __restrict__ H, const float* __restrict__ W3,
    const float* __restrict__ dis, float* __restrict__ H3, int n) {
    int row = blockIdx.x * 4 + (threadIdx.x >> 6);
    int lane = threadIdx.x & 63;
    if (row >= n) return;
    float2 v = *(const float2*)&H[(size_t)row * CH + lane * 2];
    float4 w = *(const float4*)&W3[lane * 4];
    float a0 = v.x * w.x + v.y * w.z;
    float a1 = v.x * w.y + v.y * w.w;
    #pragma unroll
    for (int off = 32; off > 0; off >>= 1) {
        a0 += __shfl_xor(a0, off, 64);
        a1 += __shfl_xor(a1, off, 64);
    }
    if (lane == 0) {
        float d = dis[row];
        H3[row * 2]     = a0 * d;
        H3[row * 2 + 1] = a1 * d;
    }
}

// ---------------- layer 3 aggregation (2 ch): thread per dst, 4-deep ----------------
__global__ void agg_out_kernel(const float* __restrict__ H3, const int* __restrict__ rs,
                               const int* __restrict__ csr, const float* __restrict__ dis,
                               const float* __restrict__ b3, float* __restrict__ out, int n) {
    int dst = blockIdx.x * blockDim.x + threadIdx.x;
    if (dst >= n) return;
    float2 acc = *(const float2*)&H3[dst * 2];
    int beg = rs[dst], end = rs[dst + 1];
    int last = end - 1;
    for (int i = beg; i < end; i += 4) {
        int i1 = i + 1 <= last ? i + 1 : last;
        int i2 = i + 2 <= last ? i + 2 : last;
        int i3 = i + 3 <= last ? i + 3 : last;
        int s0 = csr[i], s1 = csr[i1], s2 = csr[i2], s3 = csr[i3];
        float2 v0 = *(const float2*)&H3[s0 * 2];
        float2 v1 = *(const float2*)&H3[s1 * 2];
        float2 v2 = *(const float2*)&H3[s2 * 2];
        float2 v3 = *(const float2*)&H3[s3 * 2];
        float m1 = (i + 1 < end) ? 1.f : 0.f;
        float m2 = (i + 2 < end) ? 1.f : 0.f;
        float m3 = (i + 3 < end) ? 1.f : 0.f;
        acc.x += v0.x + m1 * v1.x + (m2 * v2.x + m3 * v3.x);
        acc.y += v0.y + m1 * v1.y + (m2 * v2.y + m3 * v3.y);
    }
    float d = dis[dst];
    out[dst * 2]     = fmaf(acc.x, d, b3[0]);
    out[dst * 2 + 1] = fmaf(acc.y, d, b3[1]);
}

extern "C" void kernel_launch(void* const* d_in, const int* in_sizes, int n_in,
                              void* d_out, int out_size, void* d_ws, size_t ws_size,
                              hipStream_t stream) {
    const float* x  = (const float*)d_in[0];
    const void*  ei = d_in[1];
    const float* W1 = (const float*)d_in[2];
    const float* b1 = (const float*)d_in[3];
    const float* W2 = (const float*)d_in[4];
    const float* b2 = (const float*)d_in[5];
    const float* W3 = (const float*)d_in[6];
    const float* b3 = (const float*)d_in[7];
    float* out = (float*)d_out;

    const int n = in_sizes[0] / CH;      // 100000
    const int e = in_sizes[1] / 2;       // 1600000

    char* w = (char*)d_ws;
    size_t off = 0;
    auto alloc = [&](size_t bytes) { char* p = w + off; off = (off + bytes + 255) & ~(size_t)255; return p; };
    float* bufA   = (float*)alloc((size_t)n * CH * 4);   // also aliases `binned` during CSR build
    float* bufB   = (float*)alloc((size_t)n * CH * 4);   // also aliases `hist` during CSR build
    int*   csr    = (int*)  alloc((size_t)e * 4);
    float* dis    = (float*)alloc((size_t)n * 4);
    int*   rs     = (int*)  alloc(((size_t)n + 1) * 4);
    float* H3     = (float*)alloc((size_t)n * 2 * 4);
    int*   bsum   = (int*)  alloc(1024 * 4);
    int*   btot   = (int*)  alloc(NB * 4);
    int*   bstart = (int*)  alloc((NB + 1) * 4);
    unsigned short* WhT = (unsigned short*)alloc(128 * 128 * 2);
    unsigned short* WlT = (unsigned short*)alloc(128 * 128 * 2);
    char* zbase   = w + off;
    int*   cnt    = (int*)  alloc((size_t)n * 4);
    int*   cursor = (int*)  alloc((size_t)n * 4);
    int*   flag   = (int*)  alloc(256);
    size_t zbytes = (size_t)((w + off) - zbase);

    int2* binned = (int2*)bufA;          // e*8 = 12.8MB <= 51.2MB
    int*  hist   = (int*)bufB;           // nblk*NB*4 ~ 400KB

    // bucket shift: buckets of 2^shift dsts, <= NB buckets
    int shift = 0;
    while (((n - 1) >> shift) >= NB) ++shift;

    hipMemsetAsync(zbase, 0, zbytes, stream);

    detect_kernel<<<8, 1024, 0, stream>>>((const int*)ei, flag, 2 * e);

    // ---- CSR build pass A: bin edges by dst bucket ----
    const int nblk = (e + BCHUNK - 1) / BCHUNK;   // 391 (<=512 for e<=2.09M)
    hist_kernel<<<nblk, NB, 0, stream>>>(ei, flag, hist, e, shift);
    scan_col_kernel<<<NB, 512, 0, stream>>>(hist, btot, nblk);
    scan_btot_kernel<<<1, NB, 0, stream>>>(btot, bstart);
    bin_kernel<<<nblk, NB, 0, stream>>>(ei, flag, hist, bstart, binned, e, shift);

    // ---- degrees + rs/dis ----
    count_binned_kernel<<<NB, 256, 0, stream>>>(binned, bstart, cnt);
    const int nb = (n + 255) / 256;
    scan_pass1<<<nb, 256, 0, stream>>>(cnt, bsum, n);
    scan_pass2<<<1, 1024, 0, stream>>>(bsum, nb);
    scan_pass3<<<nb, 256, 0, stream>>>(cnt, bsum, rs, dis, n, e);

    // ---- CSR build pass B: bucket-owned scatter ----
    scatter2_kernel<<<NB, 256, 0, stream>>>(binned, bstart, rs, cursor, csr);

    const int mfmaGrid = (n + 127) / 128;
    const int aggGrid  = (n + 3) / 4;

    // layer 1
    wsplit_kernel<<<64, 256, 0, stream>>>(W1, WhT, WlT);
    gemm_mfma_kernel<<<mfmaGrid, 256, 0, stream>>>(x, WhT, WlT, dis, bufA, n);
    agg128_kernel<<<aggGrid, 256, 0, stream>>>(bufA, rs, csr, dis, b1, bufB, n, 1);
    // layer 2
    wsplit_kernel<<<64, 256, 0, stream>>>(W2, WhT, WlT);
    gemm_mfma_kernel<<<mfmaGrid, 256, 0, stream>>>(bufB, WhT, WlT, dis, bufA, n);
    agg128_kernel<<<aggGrid, 256, 0, stream>>>(bufA, rs, csr, dis, b2, bufB, n, 1);
    // layer 3
    gemm_out_kernel<<<aggGrid, 256, 0, stream>>>(bufB, W3, dis, H3, n);
    agg_out_kernel<<<(n + 255) / 256, 256, 0, stream>>>(H3, rs, csr, dis, b3, out, n);
}